// Round 5
// baseline (255.765 us; speedup 1.0000x reference)
//
#include <hip/hip_runtime.h>
#include <hip/hip_bf16.h>

// MyMSA: B=4 S=2048 D=1024 H=16 DH=64. fp32 in/out. bf16 MFMA, fp32 accum.
//
// R12: attn core moved to 32x32x16 MFMA (was 16x16x32) + lacc tree-sum.
// Evidence: R6/R10/R11 (three schedules) all ~77us, MfmaUtil 42 VALU 36 ->
// duration ~ matrix(89K cy/SIMD) + VALU(66K) serialized by QK->exp2->PV
// chain. Shrink the terms:
//  * 32x32x16: 8.07cy/CU @ 32K FLOP vs 4.85 @ 16K -> -17% matrix cycles,
//    mfma count/group 36 -> 16. K-token permutation sigma(t) =
//    (t&3)+4*t3+8*t2+16*t4 baked into QKV K-write makes the S^T C-regs
//    [0..7]/[8..15] (after exp2+cvt_pk) byte-exactly the two PV B-frags.
//  * l = P@ones replaced by 15-add tree sum of exp2 values (+shfl_xor(32)
//    in epilogue): -16.5K cy matrix for +7.7K cy VALU.
// Layouts (32x32x16): A row=lane&31 k=(lane>>5)*8+j; B col=lane&31 same k;
// C col=lane&31 row=(reg&3)+8*(reg>>2)+4*(lane>>5) [m74/m101 verified].
// Staging/barrier structure = R11 (KT=128, K+V LDS double-buffer, single
// barrier/iter). qkv = R6 except the new sigma permutation for K rows.
// Standing lessons: no direct-from-global operand frags (R8/R9); barrier
// count / occupancy / LDS-read placement don't move this kernel (R10/R11).

typedef unsigned short u16;
typedef unsigned int   u32;
typedef float  f32x4   __attribute__((ext_vector_type(4)));
typedef float  f32x16  __attribute__((ext_vector_type(16)));
typedef __bf16 bf16x4  __attribute__((ext_vector_type(4)));
typedef __bf16 bf16x8  __attribute__((ext_vector_type(8)));

#define NB 4
#define SS 2048
#define DDIM 1024
#define NH 16
#define DH 64

static __device__ __forceinline__ float fexp2(float x) {
#if __has_builtin(__builtin_amdgcn_exp2f)
    return __builtin_amdgcn_exp2f(x);
#else
    return exp2f(x);
#endif
}
static __device__ __forceinline__ bf16x4 cvt4(f32x4 v) {
    return __builtin_convertvector(v, bf16x4);   // v_cvt_pk_bf16_f32 on gfx950
}
static __device__ __forceinline__ bf16x8 cvt8(f32x4 lo, f32x4 hi) {
    return __builtin_shufflevector(cvt4(lo), cvt4(hi), 0, 1, 2, 3, 4, 5, 6, 7);
}

// ---------------- Kernel 1: QKV projection (R6 + sigma K-permutation) ----
// grid: 64 * 8 = 512 blocks (bh = bid&63 -> co-XCD with attn), 256 threads.
#define WST 72   // W_lds row stride (u16): 144B

__global__ __launch_bounds__(256) void qkv_kernel(
        const float* __restrict__ x,
        const float* __restrict__ Wq, const float* __restrict__ bq,
        const float* __restrict__ Wk, const float* __restrict__ bk,
        const float* __restrict__ Wv, const float* __restrict__ bv,
        u16* __restrict__ Qw, u16* __restrict__ Kw, u16* __restrict__ Vt) {
    __shared__ __align__(16) u16 W_lds[3 * DH * WST];   // 27.6 KB

    const int tid  = threadIdx.x;
    const int w    = tid >> 6;
    const int lane = tid & 63;
    const int quad = lane >> 4;
    const int c    = lane & 15;
    const int bid  = blockIdx.x;
    const int bh   = bid & 63;
    const int s0   = (bid >> 6) * 256;
    const int b    = bh >> 4, h = bh & 15;

    // stage W fp32 -> bf16 into LDS
    {
        const float* Wsrc[3] = {Wq + h*DH*DH, Wk + h*DH*DH, Wv + h*DH*DH};
        #pragma unroll
        for (int j = 0; j < 6; ++j) {
            const int m = j >> 1;
            const int chunk = ((j & 1) << 8) + tid;      // 0..511 within mat
            const float* src = Wsrc[m] + chunk * 8;
            f32x4 lo = *(const f32x4*)src;
            f32x4 hi = *(const f32x4*)(src + 4);
            const int row = chunk >> 3, c8 = chunk & 7;
            *(bf16x8*)&W_lds[(m*DH + row) * WST + c8*8] = cvt8(lo, hi);
        }
    }
    __syncthreads();

    // per-wave W fragments, read from LDS ONCE, reused over 4 token groups
    bf16x8 wf[3][4][2];
    #pragma unroll
    for (int m = 0; m < 3; ++m)
        #pragma unroll
        for (int mt = 0; mt < 4; ++mt)
            #pragma unroll
            for (int kh = 0; kh < 2; ++kh)
                wf[m][mt][kh] = *(const bf16x8*)&W_lds[(m*DH + mt*16 + c) * WST + kh*32 + quad*8];

    f32x4 biasQK[2][4];
    float biasV[4];
    #pragma unroll
    for (int mt = 0; mt < 4; ++mt) {
        biasQK[0][mt] = *(const f32x4*)(bq + h*DH + mt*16 + quad*4);
        biasQK[1][mt] = *(const f32x4*)(bk + h*DH + mt*16 + quad*4);
        biasV[mt] = bv[h*DH + mt*16 + c];
    }

    const size_t qkbase = (size_t)bh * SS * DH;
    const size_t vtbase = (size_t)bh * DH * SS;

    #pragma unroll 1
    for (int g = 0; g < 4; ++g) {
        const int sb = s0 + w*64 + g*16;      // group tokens: sb + c
        const float* xr = x + ((size_t)(b * SS + sb + c)) * DDIM + h * DH;
        bf16x8 xb[2];
        #pragma unroll
        for (int kh = 0; kh < 2; ++kh) {
            f32x4 lo = *(const f32x4*)(xr + kh*32 + quad*8);
            f32x4 hi = *(const f32x4*)(xr + kh*32 + quad*8 + 4);
            xb[kh] = cvt8(lo, hi);
        }

        const int srow = sb + c;
        // sigma: token t -> K-matrix row within its 32-group, chosen so the
        // attn 32x32 S^T C-regs convert straight into PV B-frags.
        const int tq = srow & 31;
        const int sK = (srow & ~31) | (tq & 3)
                     | (((tq >> 3) & 1) << 2)
                     | (((tq >> 2) & 1) << 3)
                     | (((tq >> 4) & 1) << 4);

        // Q, K: swapped operands (A = W frag, B = X^T frag)
        #pragma unroll
        for (int m = 0; m < 2; ++m) {
            const float scale = (m == 0) ? 0.18033688f : 1.0f;  // 0.125*log2(e)
            u16* base = (m == 0 ? Qw : Kw) + qkbase + (size_t)(m == 0 ? srow : sK) * DH;
            #pragma unroll
            for (int mt = 0; mt < 4; ++mt) {
                f32x4 acc = {0.f, 0.f, 0.f, 0.f};
                acc = __builtin_amdgcn_mfma_f32_16x16x32_bf16(wf[m][mt][0], xb[0], acc, 0, 0, 0);
                acc = __builtin_amdgcn_mfma_f32_16x16x32_bf16(wf[m][mt][1], xb[1], acc, 0, 0, 0);
                f32x4 v = (acc + biasQK[m][mt]) * scale;
                *(bf16x4*)(base + mt*16 + quad*4) = cvt4(v);     // b64 store
            }
        }
        // V: non-swapped (A = X frag, B = W frag) -> C rows = tokens
        #pragma unroll
        for (int nt = 0; nt < 4; ++nt) {
            f32x4 acc = {0.f, 0.f, 0.f, 0.f};
            acc = __builtin_amdgcn_mfma_f32_16x16x32_bf16(xb[0], wf[2][nt][0], acc, 0, 0, 0);
            acc = __builtin_amdgcn_mfma_f32_16x16x32_bf16(xb[1], wf[2][nt][1], acc, 0, 0, 0);
            f32x4 v = acc + biasV[nt];
            u16* dst = Vt + vtbase + (size_t)(nt*16 + c) * SS + sb + quad*4;
            *(bf16x4*)dst = cvt4(v);                             // b64 along s
        }
    }
}

// ---------------- Kernel 2: flash attention, 32x32x16, qt=2x32 ----------
// grid: 64 * 8 = 512 blocks, 256 threads (4 waves x 64 q rows).
#define KT 128
#define KST 72    // K_lds row stride (u16): 144B
#define VST 136   // V_lds row stride (u16): 272B (128 cols + pad 8)

#define Z16 {0.f,0.f,0.f,0.f,0.f,0.f,0.f,0.f,0.f,0.f,0.f,0.f,0.f,0.f,0.f,0.f}

#define QT_BODY(qt, lp) do {                                                   \
        f32x16 s = Z16;                                                        \
        s = __builtin_amdgcn_mfma_f32_32x32x16_bf16(ka0, qf[qt][0], s, 0,0,0); \
        s = __builtin_amdgcn_mfma_f32_32x32x16_bf16(ka1, qf[qt][1], s, 0,0,0); \
        s = __builtin_amdgcn_mfma_f32_32x32x16_bf16(ka2, qf[qt][2], s, 0,0,0); \
        s = __builtin_amdgcn_mfma_f32_32x32x16_bf16(ka3, qf[qt][3], s, 0,0,0); \
        f32x16 e;                                                              \
        _Pragma("unroll")                                                      \
        for (int r = 0; r < 16; ++r) e[r] = fexp2(s[r]);                       \
        lp += (((e[0]+e[1])+(e[2]+e[3])) + ((e[4]+e[5])+(e[6]+e[7])))          \
            + (((e[8]+e[9])+(e[10]+e[11])) + ((e[12]+e[13])+(e[14]+e[15])));   \
        bf16x8 pf0 = cvt8((f32x4){e[0],e[1],e[2],e[3]},                        \
                          (f32x4){e[4],e[5],e[6],e[7]});                       \
        bf16x8 pf1 = cvt8((f32x4){e[8],e[9],e[10],e[11]},                      \
                          (f32x4){e[12],e[13],e[14],e[15]});                   \
        o[0][qt] = __builtin_amdgcn_mfma_f32_32x32x16_bf16(vf00, pf0, o[0][qt], 0,0,0); \
        o[0][qt] = __builtin_amdgcn_mfma_f32_32x32x16_bf16(vf01, pf1, o[0][qt], 0,0,0); \
        o[1][qt] = __builtin_amdgcn_mfma_f32_32x32x16_bf16(vf10, pf0, o[1][qt], 0,0,0); \
        o[1][qt] = __builtin_amdgcn_mfma_f32_32x32x16_bf16(vf11, pf1, o[1][qt], 0,0,0); \
    } while (0)

#define GROUP(g) do {                                                          \
        bf16x8 ka0 = *(const bf16x8*)&Kl[((g)*32 + l31) * KST +  0 + hi*8];    \
        bf16x8 ka1 = *(const bf16x8*)&Kl[((g)*32 + l31) * KST + 16 + hi*8];    \
        bf16x8 ka2 = *(const bf16x8*)&Kl[((g)*32 + l31) * KST + 32 + hi*8];    \
        bf16x8 ka3 = *(const bf16x8*)&Kl[((g)*32 + l31) * KST + 48 + hi*8];    \
        bf16x8 vf00 = *(const bf16x8*)&Vl[( 0 + l31) * VST + (g)*32 +  0 + hi*8]; \
        bf16x8 vf01 = *(const bf16x8*)&Vl[( 0 + l31) * VST + (g)*32 + 16 + hi*8]; \
        bf16x8 vf10 = *(const bf16x8*)&Vl[(32 + l31) * VST + (g)*32 +  0 + hi*8]; \
        bf16x8 vf11 = *(const bf16x8*)&Vl[(32 + l31) * VST + (g)*32 + 16 + hi*8]; \
        __builtin_amdgcn_s_setprio(1);                                         \
        QT_BODY(0, lp0);                                                       \
        QT_BODY(1, lp1);                                                       \
        __builtin_amdgcn_s_setprio(0);                                         \
    } while (0)

__global__ __launch_bounds__(256, 2) void attn_kernel(
        const u16* __restrict__ Qw, const u16* __restrict__ Kw,
        const u16* __restrict__ Vt, float* __restrict__ out) {
    __shared__ __align__(16) u16 K_lds[2][KT * KST];   // 2 x 18.4 KB
    __shared__ __align__(16) u16 V_lds[2][DH * VST];   // 2 x 17.4 KB

    const int tid  = threadIdx.x;
    const int w    = tid >> 6;
    const int lane = tid & 63;
    const int l31  = lane & 31;
    const int hi   = lane >> 5;
    const int bid  = blockIdx.x;
    const int bh   = bid & 63;           // XCD swizzle: same bh -> same XCD
    const int q0   = (bid >> 6) * 256;
    const int qw   = q0 + w * 64;        // wave's 64 q-rows (2 qt of 32)

    const u16* Qb = Qw + (size_t)bh * SS * DH;
    const u16* Kb = Kw + (size_t)bh * SS * DH;
    const u16* Vb = Vt + (size_t)bh * DH * SS;

    // Q B-frags: col q = l31, k(d) = m*16 + hi*8 + j
    bf16x8 qf[2][4];
    #pragma unroll
    for (int qt = 0; qt < 2; ++qt) {
        const u16* qrow = Qb + (size_t)(qw + qt*32 + l31) * DH;
        #pragma unroll
        for (int m = 0; m < 4; ++m)
            qf[qt][m] = *(const bf16x8*)(qrow + m*16 + hi*8);
    }

    f32x16 o[2][2];     // o[dt][qt]: O^T C-frags (col=q, rows=d-local 32)
    #pragma unroll
    for (int dt = 0; dt < 2; ++dt)
        #pragma unroll
        for (int qt = 0; qt < 2; ++qt) o[dt][qt] = (f32x16)Z16;
    float lp0 = 0.f, lp1 = 0.f;

    // staging (R11 pattern): K 128 rows x 64 u16, V 64 rows x 128 u16
    const int krow = tid >> 1;
    const int kcol = (tid & 1) * 32;
    const int kofs = krow * KST + kcol;
    const int vrow = tid >> 2;
    const int vcol = (tid & 3) * 32;
    const int vofs = vrow * VST + vcol;

    uint4 kr0 = *(const uint4*)(Kb + (size_t)krow * DH + kcol);
    uint4 kr1 = *(const uint4*)(Kb + (size_t)krow * DH + kcol + 8);
    uint4 kr2 = *(const uint4*)(Kb + (size_t)krow * DH + kcol + 16);
    uint4 kr3 = *(const uint4*)(Kb + (size_t)krow * DH + kcol + 24);
    uint4 vr0 = *(const uint4*)(Vb + (size_t)vrow * SS + vcol);
    uint4 vr1 = *(const uint4*)(Vb + (size_t)vrow * SS + vcol + 8);
    uint4 vr2 = *(const uint4*)(Vb + (size_t)vrow * SS + vcol + 16);
    uint4 vr3 = *(const uint4*)(Vb + (size_t)vrow * SS + vcol + 24);

    #pragma unroll 1
    for (int t0 = 0; t0 < SS; t0 += KT) {
        const int bsel = (t0 >> 7) & 1;
        u16* Kl = K_lds[bsel];
        u16* Vl = V_lds[bsel];
        *(uint4*)&Kl[kofs]      = kr0;
        *(uint4*)&Kl[kofs + 8]  = kr1;
        *(uint4*)&Kl[kofs + 16] = kr2;
        *(uint4*)&Kl[kofs + 24] = kr3;
        *(uint4*)&Vl[vofs]      = vr0;
        *(uint4*)&Vl[vofs + 8]  = vr1;
        *(uint4*)&Vl[vofs + 16] = vr2;
        *(uint4*)&Vl[vofs + 24] = vr3;
        __syncthreads();                       // single barrier per iter
        int tn = t0 + KT; if (tn >= SS) tn = 0;    // wrap: harmless reload
        kr0 = *(const uint4*)(Kb + (size_t)(tn + krow) * DH + kcol);
        kr1 = *(const uint4*)(Kb + (size_t)(tn + krow) * DH + kcol + 8);
        kr2 = *(const uint4*)(Kb + (size_t)(tn + krow) * DH + kcol + 16);
        kr3 = *(const uint4*)(Kb + (size_t)(tn + krow) * DH + kcol + 24);
        vr0 = *(const uint4*)(Vb + (size_t)vrow * SS + tn + vcol);
        vr1 = *(const uint4*)(Vb + (size_t)vrow * SS + tn + vcol + 8);
        vr2 = *(const uint4*)(Vb + (size_t)vrow * SS + tn + vcol + 16);
        vr3 = *(const uint4*)(Vb + (size_t)vrow * SS + tn + vcol + 24);

        GROUP(0);
        GROUP(1);
        GROUP(2);
        GROUP(3);
    }

    // epilogue: lane holds q = qw + qt*32 + l31; its 16 d-values per dt at
    // d = dt*32 + 8*rq + 4*hi + (0..3). l needs hi-half combine.
    const int b = bh >> 4, h = bh & 15;
    const float lw0 = lp0 + __shfl_xor(lp0, 32, 64);
    const float lw1 = lp1 + __shfl_xor(lp1, 32, 64);
    #pragma unroll
    for (int qt = 0; qt < 2; ++qt) {
        const float inv = 1.0f / (qt == 0 ? lw0 : lw1);
        const int token = qw + qt*32 + l31;
        float* orow = out + ((size_t)b * SS + token) * DDIM + h * DH;
        #pragma unroll
        for (int dt = 0; dt < 2; ++dt) {
            #pragma unroll
            for (int rq = 0; rq < 4; ++rq) {
                f32x4 vv = {o[dt][qt][4*rq+0], o[dt][qt][4*rq+1],
                            o[dt][qt][4*rq+2], o[dt][qt][4*rq+3]};
                vv = vv * inv;
                *(f32x4*)(orow + dt*32 + 8*rq + 4*hi) = vv;
            }
        }
    }
}

extern "C" void kernel_launch(void* const* d_in, const int* in_sizes, int n_in,
                              void* d_out, int out_size, void* d_ws, size_t ws_size,
                              hipStream_t stream) {
    const float* x  = (const float*)d_in[0];
    const float* Wq = (const float*)d_in[1];
    const float* bq = (const float*)d_in[2];
    const float* Wk = (const float*)d_in[3];
    const float* bk = (const float*)d_in[4];
    const float* Wv = (const float*)d_in[5];
    const float* bv = (const float*)d_in[6];

    // ws: Qw[bh][s][d], Kw[bh][s'][d] (s sigma-permuted per 32), Vt[bh][d][s]
    u16* Qw = (u16*)d_ws;
    u16* Kw = Qw + (size_t)NB * NH * SS * DH;
    u16* Vt = Kw + (size_t)NB * NH * SS * DH;

    qkv_kernel<<<64 * (SS / 256), 256, 0, stream>>>(
        x, Wq, bq, Wk, bk, Wv, bv, Qw, Kw, Vt);
    attn_kernel<<<64 * (SS / 256), 256, 0, stream>>>(Qw, Kw, Vt, (float*)d_out);
}

// Round 6
// 185.965 us; speedup vs baseline: 1.3753x; 1.3753x over previous
//
#include <hip/hip_runtime.h>
#include <hip/hip_bf16.h>

// MyMSA: B=4 S=2048 D=1024 H=16 DH=64. fp32 in/out. bf16 MFMA, fp32 accum.
//
// R13 = R12 (32x32x16 MFMA + sigma K-permutation + lacc tree-sum; math
// verified passing) with register pressure cut below the spill cliff:
//  * qt 2->1: 32 q-rows/wave, o[2] f32x16 (32 regs), qf[4] (16). grid
//    64*16=1024 blocks x 256 thr (4 waves x 32 q).
//  * KT 128->64: staging regs 32->16 (KT was perf-neutral per R11).
//  * exp2 computed in place in the S C-regs (no second f32x16).
// R12 lesson: peak live ~192 unified -> allocator put accum in AGPR,
// capped VGPR at 128, spilled ~28 dwords/thread/iter (WRITE_SIZE 264MB,
// FETCH +32MB, MfmaUtil 18). Peak here ~130 -> no spill expected.
// Model (R12-corrected): MFMA rate ~1000 FLOP/cy/SIMD shared ->
// matrix 66K cy/SIMD (32x32, no lacc-MFMA) + VALU ~74K, serialized via
// QK->exp2->PV chain -> ~66us attn.
// Standing lessons: no direct-from-global operand frags (R8/R9); barrier
// count / occupancy / LDS-read placement don't move this kernel (R10/R11).

typedef unsigned short u16;
typedef unsigned int   u32;
typedef float  f32x4   __attribute__((ext_vector_type(4)));
typedef float  f32x16  __attribute__((ext_vector_type(16)));
typedef __bf16 bf16x4  __attribute__((ext_vector_type(4)));
typedef __bf16 bf16x8  __attribute__((ext_vector_type(8)));

#define NB 4
#define SS 2048
#define DDIM 1024
#define NH 16
#define DH 64

static __device__ __forceinline__ float fexp2(float x) {
#if __has_builtin(__builtin_amdgcn_exp2f)
    return __builtin_amdgcn_exp2f(x);
#else
    return exp2f(x);
#endif
}
static __device__ __forceinline__ bf16x4 cvt4(f32x4 v) {
    return __builtin_convertvector(v, bf16x4);   // v_cvt_pk_bf16_f32 on gfx950
}
static __device__ __forceinline__ bf16x8 cvt8(f32x4 lo, f32x4 hi) {
    return __builtin_shufflevector(cvt4(lo), cvt4(hi), 0, 1, 2, 3, 4, 5, 6, 7);
}

// ---------------- Kernel 1: QKV projection (R12 verbatim) ----------------
// grid: 64 * 8 = 512 blocks (bh = bid&63 -> co-XCD with attn), 256 threads.
#define WST 72   // W_lds row stride (u16): 144B

__global__ __launch_bounds__(256) void qkv_kernel(
        const float* __restrict__ x,
        const float* __restrict__ Wq, const float* __restrict__ bq,
        const float* __restrict__ Wk, const float* __restrict__ bk,
        const float* __restrict__ Wv, const float* __restrict__ bv,
        u16* __restrict__ Qw, u16* __restrict__ Kw, u16* __restrict__ Vt) {
    __shared__ __align__(16) u16 W_lds[3 * DH * WST];   // 27.6 KB

    const int tid  = threadIdx.x;
    const int w    = tid >> 6;
    const int lane = tid & 63;
    const int quad = lane >> 4;
    const int c    = lane & 15;
    const int bid  = blockIdx.x;
    const int bh   = bid & 63;
    const int s0   = (bid >> 6) * 256;
    const int b    = bh >> 4, h = bh & 15;

    // stage W fp32 -> bf16 into LDS
    {
        const float* Wsrc[3] = {Wq + h*DH*DH, Wk + h*DH*DH, Wv + h*DH*DH};
        #pragma unroll
        for (int j = 0; j < 6; ++j) {
            const int m = j >> 1;
            const int chunk = ((j & 1) << 8) + tid;      // 0..511 within mat
            const float* src = Wsrc[m] + chunk * 8;
            f32x4 lo = *(const f32x4*)src;
            f32x4 hi = *(const f32x4*)(src + 4);
            const int row = chunk >> 3, c8 = chunk & 7;
            *(bf16x8*)&W_lds[(m*DH + row) * WST + c8*8] = cvt8(lo, hi);
        }
    }
    __syncthreads();

    // per-wave W fragments, read from LDS ONCE, reused over 4 token groups
    bf16x8 wf[3][4][2];
    #pragma unroll
    for (int m = 0; m < 3; ++m)
        #pragma unroll
        for (int mt = 0; mt < 4; ++mt)
            #pragma unroll
            for (int kh = 0; kh < 2; ++kh)
                wf[m][mt][kh] = *(const bf16x8*)&W_lds[(m*DH + mt*16 + c) * WST + kh*32 + quad*8];

    f32x4 biasQK[2][4];
    float biasV[4];
    #pragma unroll
    for (int mt = 0; mt < 4; ++mt) {
        biasQK[0][mt] = *(const f32x4*)(bq + h*DH + mt*16 + quad*4);
        biasQK[1][mt] = *(const f32x4*)(bk + h*DH + mt*16 + quad*4);
        biasV[mt] = bv[h*DH + mt*16 + c];
    }

    const size_t qkbase = (size_t)bh * SS * DH;
    const size_t vtbase = (size_t)bh * DH * SS;

    #pragma unroll 1
    for (int g = 0; g < 4; ++g) {
        const int sb = s0 + w*64 + g*16;      // group tokens: sb + c
        const float* xr = x + ((size_t)(b * SS + sb + c)) * DDIM + h * DH;
        bf16x8 xb[2];
        #pragma unroll
        for (int kh = 0; kh < 2; ++kh) {
            f32x4 lo = *(const f32x4*)(xr + kh*32 + quad*8);
            f32x4 hi = *(const f32x4*)(xr + kh*32 + quad*8 + 4);
            xb[kh] = cvt8(lo, hi);
        }

        const int srow = sb + c;
        // sigma: token t -> K-matrix row within its 32-group, chosen so the
        // attn 32x32 S^T C-regs convert straight into PV B-frags.
        const int tq = srow & 31;
        const int sK = (srow & ~31) | (tq & 3)
                     | (((tq >> 3) & 1) << 2)
                     | (((tq >> 2) & 1) << 3)
                     | (((tq >> 4) & 1) << 4);

        // Q, K: swapped operands (A = W frag, B = X^T frag)
        #pragma unroll
        for (int m = 0; m < 2; ++m) {
            const float scale = (m == 0) ? 0.18033688f : 1.0f;  // 0.125*log2(e)
            u16* base = (m == 0 ? Qw : Kw) + qkbase + (size_t)(m == 0 ? srow : sK) * DH;
            #pragma unroll
            for (int mt = 0; mt < 4; ++mt) {
                f32x4 acc = {0.f, 0.f, 0.f, 0.f};
                acc = __builtin_amdgcn_mfma_f32_16x16x32_bf16(wf[m][mt][0], xb[0], acc, 0, 0, 0);
                acc = __builtin_amdgcn_mfma_f32_16x16x32_bf16(wf[m][mt][1], xb[1], acc, 0, 0, 0);
                f32x4 v = (acc + biasQK[m][mt]) * scale;
                *(bf16x4*)(base + mt*16 + quad*4) = cvt4(v);     // b64 store
            }
        }
        // V: non-swapped (A = X frag, B = W frag) -> C rows = tokens
        #pragma unroll
        for (int nt = 0; nt < 4; ++nt) {
            f32x4 acc = {0.f, 0.f, 0.f, 0.f};
            acc = __builtin_amdgcn_mfma_f32_16x16x32_bf16(xb[0], wf[2][nt][0], acc, 0, 0, 0);
            acc = __builtin_amdgcn_mfma_f32_16x16x32_bf16(xb[1], wf[2][nt][1], acc, 0, 0, 0);
            f32x4 v = acc + biasV[nt];
            u16* dst = Vt + vtbase + (size_t)(nt*16 + c) * SS + sb + quad*4;
            *(bf16x4*)dst = cvt4(v);                             // b64 along s
        }
    }
}

// ---------------- Kernel 2: flash attention, 32x32x16, qt=1 -------------
// grid: 64 * 16 = 1024 blocks, 256 threads (4 waves x 32 q rows).
#define KT 64
#define KST 72    // K_lds row stride (u16): 144B
#define VST 72    // V_lds row stride (u16): 144B

#define Z16 {0.f,0.f,0.f,0.f,0.f,0.f,0.f,0.f,0.f,0.f,0.f,0.f,0.f,0.f,0.f,0.f}

#define GROUP(g) do {                                                          \
        bf16x8 ka0 = *(const bf16x8*)&Kl[((g)*32 + l31) * KST +  0 + hi*8];    \
        bf16x8 ka1 = *(const bf16x8*)&Kl[((g)*32 + l31) * KST + 16 + hi*8];    \
        bf16x8 ka2 = *(const bf16x8*)&Kl[((g)*32 + l31) * KST + 32 + hi*8];    \
        bf16x8 ka3 = *(const bf16x8*)&Kl[((g)*32 + l31) * KST + 48 + hi*8];    \
        bf16x8 vf00 = *(const bf16x8*)&Vl[( 0 + l31) * VST + (g)*32 +  0 + hi*8]; \
        bf16x8 vf01 = *(const bf16x8*)&Vl[( 0 + l31) * VST + (g)*32 + 16 + hi*8]; \
        bf16x8 vf10 = *(const bf16x8*)&Vl[(32 + l31) * VST + (g)*32 +  0 + hi*8]; \
        bf16x8 vf11 = *(const bf16x8*)&Vl[(32 + l31) * VST + (g)*32 + 16 + hi*8]; \
        __builtin_amdgcn_s_setprio(1);                                         \
        f32x16 s = Z16;                                                        \
        s = __builtin_amdgcn_mfma_f32_32x32x16_bf16(ka0, qf[0], s, 0,0,0);     \
        s = __builtin_amdgcn_mfma_f32_32x32x16_bf16(ka1, qf[1], s, 0,0,0);     \
        s = __builtin_amdgcn_mfma_f32_32x32x16_bf16(ka2, qf[2], s, 0,0,0);     \
        s = __builtin_amdgcn_mfma_f32_32x32x16_bf16(ka3, qf[3], s, 0,0,0);     \
        _Pragma("unroll")                                                      \
        for (int r = 0; r < 16; ++r) s[r] = fexp2(s[r]);                       \
        lp += (((s[0]+s[1])+(s[2]+s[3])) + ((s[4]+s[5])+(s[6]+s[7])))          \
            + (((s[8]+s[9])+(s[10]+s[11])) + ((s[12]+s[13])+(s[14]+s[15])));   \
        bf16x8 pf0 = cvt8((f32x4){s[0],s[1],s[2],s[3]},                        \
                          (f32x4){s[4],s[5],s[6],s[7]});                       \
        bf16x8 pf1 = cvt8((f32x4){s[8],s[9],s[10],s[11]},                      \
                          (f32x4){s[12],s[13],s[14],s[15]});                   \
        o0 = __builtin_amdgcn_mfma_f32_32x32x16_bf16(vf00, pf0, o0, 0,0,0);    \
        o0 = __builtin_amdgcn_mfma_f32_32x32x16_bf16(vf01, pf1, o0, 0,0,0);    \
        o1 = __builtin_amdgcn_mfma_f32_32x32x16_bf16(vf10, pf0, o1, 0,0,0);    \
        o1 = __builtin_amdgcn_mfma_f32_32x32x16_bf16(vf11, pf1, o1, 0,0,0);    \
        __builtin_amdgcn_s_setprio(0);                                         \
    } while (0)

__global__ __launch_bounds__(256, 2) void attn_kernel(
        const u16* __restrict__ Qw, const u16* __restrict__ Kw,
        const u16* __restrict__ Vt, float* __restrict__ out) {
    __shared__ __align__(16) u16 K_lds[2][KT * KST];   // 2 x 9.2 KB
    __shared__ __align__(16) u16 V_lds[2][DH * VST];   // 2 x 9.2 KB

    const int tid  = threadIdx.x;
    const int w    = tid >> 6;
    const int lane = tid & 63;
    const int l31  = lane & 31;
    const int hi   = lane >> 5;
    const int bid  = blockIdx.x;
    const int bh   = bid & 63;           // XCD swizzle: same bh -> same XCD
    const int q0   = (bid >> 6) * 128;
    const int qw   = q0 + w * 32;        // wave's 32 q-rows

    const u16* Qb = Qw + (size_t)bh * SS * DH;
    const u16* Kb = Kw + (size_t)bh * SS * DH;
    const u16* Vb = Vt + (size_t)bh * DH * SS;

    // Q B-frags: col q = l31, k(d) = m*16 + hi*8 + j
    bf16x8 qf[4];
    {
        const u16* qrow = Qb + (size_t)(qw + l31) * DH;
        #pragma unroll
        for (int m = 0; m < 4; ++m)
            qf[m] = *(const bf16x8*)(qrow + m*16 + hi*8);
    }

    f32x16 o0 = Z16, o1 = Z16;   // O^T C-frags (col=q, rows=d 0-31 / 32-63)
    float lp = 0.f;

    // staging: row = tid>>2 (0..63), 16 u16 cols per thread (2x uint4)
    const int strow = tid >> 2;
    const int stcol = (tid & 3) * 16;
    const int kofs  = strow * KST + stcol;
    const int vofs  = strow * VST + stcol;

    uint4 kr0 = *(const uint4*)(Kb + (size_t)strow * DH + stcol);
    uint4 kr1 = *(const uint4*)(Kb + (size_t)strow * DH + stcol + 8);
    uint4 vr0 = *(const uint4*)(Vb + (size_t)strow * SS + stcol);
    uint4 vr1 = *(const uint4*)(Vb + (size_t)strow * SS + stcol + 8);

    #pragma unroll 1
    for (int t0 = 0; t0 < SS; t0 += KT) {
        const int bsel = (t0 >> 6) & 1;
        u16* Kl = K_lds[bsel];
        u16* Vl = V_lds[bsel];
        *(uint4*)&Kl[kofs]     = kr0;
        *(uint4*)&Kl[kofs + 8] = kr1;
        *(uint4*)&Vl[vofs]     = vr0;
        *(uint4*)&Vl[vofs + 8] = vr1;
        __syncthreads();                       // single barrier per iter
        int tn = t0 + KT; if (tn >= SS) tn = 0;    // wrap: harmless reload
        kr0 = *(const uint4*)(Kb + (size_t)(tn + strow) * DH + stcol);
        kr1 = *(const uint4*)(Kb + (size_t)(tn + strow) * DH + stcol + 8);
        vr0 = *(const uint4*)(Vb + (size_t)strow * SS + tn + stcol);
        vr1 = *(const uint4*)(Vb + (size_t)strow * SS + tn + stcol + 8);

        GROUP(0);
        GROUP(1);
    }

    // epilogue: lane holds q = qw + l31; d = dt*32 + 8*rq + 4*hi + (0..3).
    const int b = bh >> 4, h = bh & 15;
    const float lw = lp + __shfl_xor(lp, 32, 64);
    const float inv = 1.0f / lw;
    const int token = qw + l31;
    float* orow = out + ((size_t)b * SS + token) * DDIM + h * DH;
    #pragma unroll
    for (int rq = 0; rq < 4; ++rq) {
        f32x4 v0 = {o0[4*rq+0], o0[4*rq+1], o0[4*rq+2], o0[4*rq+3]};
        f32x4 v1 = {o1[4*rq+0], o1[4*rq+1], o1[4*rq+2], o1[4*rq+3]};
        v0 = v0 * inv;
        v1 = v1 * inv;
        *(f32x4*)(orow +      8*rq + 4*hi) = v0;
        *(f32x4*)(orow + 32 + 8*rq + 4*hi) = v1;
    }
}

extern "C" void kernel_launch(void* const* d_in, const int* in_sizes, int n_in,
                              void* d_out, int out_size, void* d_ws, size_t ws_size,
                              hipStream_t stream) {
    const float* x  = (const float*)d_in[0];
    const float* Wq = (const float*)d_in[1];
    const float* bq = (const float*)d_in[2];
    const float* Wk = (const float*)d_in[3];
    const float* bk = (const float*)d_in[4];
    const float* Wv = (const float*)d_in[5];
    const float* bv = (const float*)d_in[6];

    // ws: Qw[bh][s][d], Kw[bh][s'][d] (s sigma-permuted per 32), Vt[bh][d][s]
    u16* Qw = (u16*)d_ws;
    u16* Kw = Qw + (size_t)NB * NH * SS * DH;
    u16* Vt = Kw + (size_t)NB * NH * SS * DH;

    qkv_kernel<<<64 * (SS / 256), 256, 0, stream>>>(
        x, Wq, bq, Wk, bk, Wv, bv, Qw, Kw, Vt);
    attn_kernel<<<64 * (SS / 128), 256, 0, stream>>>(Qw, Kw, Vt, (float*)d_out);
}

// Round 7
// 185.045 us; speedup vs baseline: 1.3822x; 1.0050x over previous
//
#include <hip/hip_runtime.h>
#include <hip/hip_bf16.h>

// MyMSA: B=4 S=2048 D=1024 H=16 DH=64. fp32 in/out. bf16 MFMA, fp32 accum.
//
// R14 = R13 (32x32x16 + sigma K-perm + tree-sum lacc, verified) with the
// occupancy lever: 512-thread blocks (8 waves) share ONE K/V staging ->
// LDS/block unchanged (36.9KB) but 2 blocks/CU = 16 waves/CU = 4 waves/
// SIMD (R13: 2). Mechanism: MFMA blocks its issuing wave on CDNA, so
// QK->exp2->PV stalls can only be hidden by OTHER waves on the SIMD;
// 6 schedule variants at 2 waves/SIMD all hit 77-80us because none raised
// this. Per-wave math/frag reads byte-identical to R13. Staging global
// reads per CU halve (8 waves amortize one stage). setprio now wraps only
// MFMA clusters (T5 proper form).
// Standing lessons: no direct-from-global operand frags (R8/R9); spill
// cliff at ~130 live regs (R12); barrier count / LDS-read placement are
// not levers (R10/R11).

typedef unsigned short u16;
typedef unsigned int   u32;
typedef float  f32x4   __attribute__((ext_vector_type(4)));
typedef float  f32x16  __attribute__((ext_vector_type(16)));
typedef __bf16 bf16x4  __attribute__((ext_vector_type(4)));
typedef __bf16 bf16x8  __attribute__((ext_vector_type(8)));

#define NB 4
#define SS 2048
#define DDIM 1024
#define NH 16
#define DH 64

static __device__ __forceinline__ float fexp2(float x) {
#if __has_builtin(__builtin_amdgcn_exp2f)
    return __builtin_amdgcn_exp2f(x);
#else
    return exp2f(x);
#endif
}
static __device__ __forceinline__ bf16x4 cvt4(f32x4 v) {
    return __builtin_convertvector(v, bf16x4);   // v_cvt_pk_bf16_f32 on gfx950
}
static __device__ __forceinline__ bf16x8 cvt8(f32x4 lo, f32x4 hi) {
    return __builtin_shufflevector(cvt4(lo), cvt4(hi), 0, 1, 2, 3, 4, 5, 6, 7);
}

// ---------------- Kernel 1: QKV projection (R12 verbatim) ----------------
// grid: 64 * 8 = 512 blocks (bh = bid&63 -> co-XCD with attn), 256 threads.
#define WST 72   // W_lds row stride (u16): 144B

__global__ __launch_bounds__(256) void qkv_kernel(
        const float* __restrict__ x,
        const float* __restrict__ Wq, const float* __restrict__ bq,
        const float* __restrict__ Wk, const float* __restrict__ bk,
        const float* __restrict__ Wv, const float* __restrict__ bv,
        u16* __restrict__ Qw, u16* __restrict__ Kw, u16* __restrict__ Vt) {
    __shared__ __align__(16) u16 W_lds[3 * DH * WST];   // 27.6 KB

    const int tid  = threadIdx.x;
    const int w    = tid >> 6;
    const int lane = tid & 63;
    const int quad = lane >> 4;
    const int c    = lane & 15;
    const int bid  = blockIdx.x;
    const int bh   = bid & 63;
    const int s0   = (bid >> 6) * 256;
    const int b    = bh >> 4, h = bh & 15;

    // stage W fp32 -> bf16 into LDS
    {
        const float* Wsrc[3] = {Wq + h*DH*DH, Wk + h*DH*DH, Wv + h*DH*DH};
        #pragma unroll
        for (int j = 0; j < 6; ++j) {
            const int m = j >> 1;
            const int chunk = ((j & 1) << 8) + tid;      // 0..511 within mat
            const float* src = Wsrc[m] + chunk * 8;
            f32x4 lo = *(const f32x4*)src;
            f32x4 hi = *(const f32x4*)(src + 4);
            const int row = chunk >> 3, c8 = chunk & 7;
            *(bf16x8*)&W_lds[(m*DH + row) * WST + c8*8] = cvt8(lo, hi);
        }
    }
    __syncthreads();

    // per-wave W fragments, read from LDS ONCE, reused over 4 token groups
    bf16x8 wf[3][4][2];
    #pragma unroll
    for (int m = 0; m < 3; ++m)
        #pragma unroll
        for (int mt = 0; mt < 4; ++mt)
            #pragma unroll
            for (int kh = 0; kh < 2; ++kh)
                wf[m][mt][kh] = *(const bf16x8*)&W_lds[(m*DH + mt*16 + c) * WST + kh*32 + quad*8];

    f32x4 biasQK[2][4];
    float biasV[4];
    #pragma unroll
    for (int mt = 0; mt < 4; ++mt) {
        biasQK[0][mt] = *(const f32x4*)(bq + h*DH + mt*16 + quad*4);
        biasQK[1][mt] = *(const f32x4*)(bk + h*DH + mt*16 + quad*4);
        biasV[mt] = bv[h*DH + mt*16 + c];
    }

    const size_t qkbase = (size_t)bh * SS * DH;
    const size_t vtbase = (size_t)bh * DH * SS;

    #pragma unroll 1
    for (int g = 0; g < 4; ++g) {
        const int sb = s0 + w*64 + g*16;      // group tokens: sb + c
        const float* xr = x + ((size_t)(b * SS + sb + c)) * DDIM + h * DH;
        bf16x8 xb[2];
        #pragma unroll
        for (int kh = 0; kh < 2; ++kh) {
            f32x4 lo = *(const f32x4*)(xr + kh*32 + quad*8);
            f32x4 hi = *(const f32x4*)(xr + kh*32 + quad*8 + 4);
            xb[kh] = cvt8(lo, hi);
        }

        const int srow = sb + c;
        // sigma: token t -> K-matrix row within its 32-group, chosen so the
        // attn 32x32 S^T C-regs convert straight into PV B-frags.
        const int tq = srow & 31;
        const int sK = (srow & ~31) | (tq & 3)
                     | (((tq >> 3) & 1) << 2)
                     | (((tq >> 2) & 1) << 3)
                     | (((tq >> 4) & 1) << 4);

        // Q, K: swapped operands (A = W frag, B = X^T frag)
        #pragma unroll
        for (int m = 0; m < 2; ++m) {
            const float scale = (m == 0) ? 0.18033688f : 1.0f;  // 0.125*log2(e)
            u16* base = (m == 0 ? Qw : Kw) + qkbase + (size_t)(m == 0 ? srow : sK) * DH;
            #pragma unroll
            for (int mt = 0; mt < 4; ++mt) {
                f32x4 acc = {0.f, 0.f, 0.f, 0.f};
                acc = __builtin_amdgcn_mfma_f32_16x16x32_bf16(wf[m][mt][0], xb[0], acc, 0, 0, 0);
                acc = __builtin_amdgcn_mfma_f32_16x16x32_bf16(wf[m][mt][1], xb[1], acc, 0, 0, 0);
                f32x4 v = (acc + biasQK[m][mt]) * scale;
                *(bf16x4*)(base + mt*16 + quad*4) = cvt4(v);     // b64 store
            }
        }
        // V: non-swapped (A = X frag, B = W frag) -> C rows = tokens
        #pragma unroll
        for (int nt = 0; nt < 4; ++nt) {
            f32x4 acc = {0.f, 0.f, 0.f, 0.f};
            acc = __builtin_amdgcn_mfma_f32_16x16x32_bf16(xb[0], wf[2][nt][0], acc, 0, 0, 0);
            acc = __builtin_amdgcn_mfma_f32_16x16x32_bf16(xb[1], wf[2][nt][1], acc, 0, 0, 0);
            f32x4 v = acc + biasV[nt];
            u16* dst = Vt + vtbase + (size_t)(nt*16 + c) * SS + sb + quad*4;
            *(bf16x4*)dst = cvt4(v);                             // b64 along s
        }
    }
}

// ---------------- Kernel 2: flash attention, 32x32x16, 8-wave blocks ----
// grid: 64 * 8 = 512 blocks, 512 threads (8 waves x 32 q rows = 256 q).
#define KT 64
#define KST 72    // K_lds row stride (u16): 144B
#define VST 72    // V_lds row stride (u16): 144B

#define Z16 {0.f,0.f,0.f,0.f,0.f,0.f,0.f,0.f,0.f,0.f,0.f,0.f,0.f,0.f,0.f,0.f}

#define GROUP(g) do {                                                          \
        bf16x8 ka0 = *(const bf16x8*)&Kl[((g)*32 + l31) * KST +  0 + hi*8];    \
        bf16x8 ka1 = *(const bf16x8*)&Kl[((g)*32 + l31) * KST + 16 + hi*8];    \
        bf16x8 ka2 = *(const bf16x8*)&Kl[((g)*32 + l31) * KST + 32 + hi*8];    \
        bf16x8 ka3 = *(const bf16x8*)&Kl[((g)*32 + l31) * KST + 48 + hi*8];    \
        bf16x8 vf00 = *(const bf16x8*)&Vl[( 0 + l31) * VST + (g)*32 +  0 + hi*8]; \
        bf16x8 vf01 = *(const bf16x8*)&Vl[( 0 + l31) * VST + (g)*32 + 16 + hi*8]; \
        bf16x8 vf10 = *(const bf16x8*)&Vl[(32 + l31) * VST + (g)*32 +  0 + hi*8]; \
        bf16x8 vf11 = *(const bf16x8*)&Vl[(32 + l31) * VST + (g)*32 + 16 + hi*8]; \
        f32x16 s = Z16;                                                        \
        __builtin_amdgcn_s_setprio(1);                                         \
        s = __builtin_amdgcn_mfma_f32_32x32x16_bf16(ka0, qf[0], s, 0,0,0);     \
        s = __builtin_amdgcn_mfma_f32_32x32x16_bf16(ka1, qf[1], s, 0,0,0);     \
        s = __builtin_amdgcn_mfma_f32_32x32x16_bf16(ka2, qf[2], s, 0,0,0);     \
        s = __builtin_amdgcn_mfma_f32_32x32x16_bf16(ka3, qf[3], s, 0,0,0);     \
        __builtin_amdgcn_s_setprio(0);                                         \
        _Pragma("unroll")                                                      \
        for (int r = 0; r < 16; ++r) s[r] = fexp2(s[r]);                       \
        lp += (((s[0]+s[1])+(s[2]+s[3])) + ((s[4]+s[5])+(s[6]+s[7])))          \
            + (((s[8]+s[9])+(s[10]+s[11])) + ((s[12]+s[13])+(s[14]+s[15])));   \
        bf16x8 pf0 = cvt8((f32x4){s[0],s[1],s[2],s[3]},                        \
                          (f32x4){s[4],s[5],s[6],s[7]});                       \
        bf16x8 pf1 = cvt8((f32x4){s[8],s[9],s[10],s[11]},                      \
                          (f32x4){s[12],s[13],s[14],s[15]});                   \
        __builtin_amdgcn_s_setprio(1);                                         \
        o0 = __builtin_amdgcn_mfma_f32_32x32x16_bf16(vf00, pf0, o0, 0,0,0);    \
        o0 = __builtin_amdgcn_mfma_f32_32x32x16_bf16(vf01, pf1, o0, 0,0,0);    \
        o1 = __builtin_amdgcn_mfma_f32_32x32x16_bf16(vf10, pf0, o1, 0,0,0);    \
        o1 = __builtin_amdgcn_mfma_f32_32x32x16_bf16(vf11, pf1, o1, 0,0,0);    \
        __builtin_amdgcn_s_setprio(0);                                         \
    } while (0)

__global__ __launch_bounds__(512, 3) void attn_kernel(
        const u16* __restrict__ Qw, const u16* __restrict__ Kw,
        const u16* __restrict__ Vt, float* __restrict__ out) {
    __shared__ __align__(16) u16 K_lds[2][KT * KST];   // 2 x 9.2 KB
    __shared__ __align__(16) u16 V_lds[2][DH * VST];   // 2 x 9.2 KB

    const int tid  = threadIdx.x;
    const int w    = tid >> 6;           // 0..7
    const int lane = tid & 63;
    const int l31  = lane & 31;
    const int hi   = lane >> 5;
    const int bid  = blockIdx.x;
    const int bh   = bid & 63;           // XCD swizzle: same bh -> same XCD
    const int q0   = (bid >> 6) * 256;
    const int qw   = q0 + w * 32;        // wave's 32 q-rows

    const u16* Qb = Qw + (size_t)bh * SS * DH;
    const u16* Kb = Kw + (size_t)bh * SS * DH;
    const u16* Vb = Vt + (size_t)bh * DH * SS;

    // Q B-frags: col q = l31, k(d) = m*16 + hi*8 + j
    bf16x8 qf[4];
    {
        const u16* qrow = Qb + (size_t)(qw + l31) * DH;
        #pragma unroll
        for (int m = 0; m < 4; ++m)
            qf[m] = *(const bf16x8*)(qrow + m*16 + hi*8);
    }

    f32x16 o0 = Z16, o1 = Z16;   // O^T C-frags (col=q, rows=d 0-31 / 32-63)
    float lp = 0.f;

    // staging: 512 threads, 8/row, one uint4 (8 u16) each for K and V
    const int srow = tid >> 3;           // 0..63
    const int sc8  = (tid & 7) * 8;      // 0..56
    const int kofs = srow * KST + sc8;
    const int vofs = srow * VST + sc8;

    uint4 kr = *(const uint4*)(Kb + (size_t)srow * DH + sc8);
    uint4 vr = *(const uint4*)(Vb + (size_t)srow * SS + sc8);

    #pragma unroll 1
    for (int t0 = 0; t0 < SS; t0 += KT) {
        const int bsel = (t0 >> 6) & 1;
        u16* Kl = K_lds[bsel];
        u16* Vl = V_lds[bsel];
        *(uint4*)&Kl[kofs] = kr;
        *(uint4*)&Vl[vofs] = vr;
        __syncthreads();                       // single barrier per iter
        int tn = t0 + KT; if (tn >= SS) tn = 0;    // wrap: harmless reload
        kr = *(const uint4*)(Kb + (size_t)(tn + srow) * DH + sc8);
        vr = *(const uint4*)(Vb + (size_t)srow * SS + tn + sc8);

        GROUP(0);
        GROUP(1);
    }

    // epilogue: lane holds q = qw + l31; d = dt*32 + 8*rq + 4*hi + (0..3).
    const int b = bh >> 4, h = bh & 15;
    const float lw = lp + __shfl_xor(lp, 32, 64);
    const float inv = 1.0f / lw;
    const int token = qw + l31;
    float* orow = out + ((size_t)b * SS + token) * DDIM + h * DH;
    #pragma unroll
    for (int rq = 0; rq < 4; ++rq) {
        f32x4 v0 = {o0[4*rq+0], o0[4*rq+1], o0[4*rq+2], o0[4*rq+3]};
        f32x4 v1 = {o1[4*rq+0], o1[4*rq+1], o1[4*rq+2], o1[4*rq+3]};
        v0 = v0 * inv;
        v1 = v1 * inv;
        *(f32x4*)(orow +      8*rq + 4*hi) = v0;
        *(f32x4*)(orow + 32 + 8*rq + 4*hi) = v1;
    }
}

extern "C" void kernel_launch(void* const* d_in, const int* in_sizes, int n_in,
                              void* d_out, int out_size, void* d_ws, size_t ws_size,
                              hipStream_t stream) {
    const float* x  = (const float*)d_in[0];
    const float* Wq = (const float*)d_in[1];
    const float* bq = (const float*)d_in[2];
    const float* Wk = (const float*)d_in[3];
    const float* bk = (const float*)d_in[4];
    const float* Wv = (const float*)d_in[5];
    const float* bv = (const float*)d_in[6];

    // ws: Qw[bh][s][d], Kw[bh][s'][d] (s sigma-permuted per 32), Vt[bh][d][s]
    u16* Qw = (u16*)d_ws;
    u16* Kw = Qw + (size_t)NB * NH * SS * DH;
    u16* Vt = Kw + (size_t)NB * NH * SS * DH;

    qkv_kernel<<<64 * (SS / 256), 256, 0, stream>>>(
        x, Wq, bq, Wk, bk, Wv, bv, Qw, Kw, Vt);
    attn_kernel<<<64 * (SS / 256), 512, 0, stream>>>(Qw, Kw, Vt, (float*)d_out);
}